// Round 3
// baseline (120.203 us; speedup 1.0000x reference)
//
#include <hip/hip_runtime.h>

typedef short s16x8 __attribute__((ext_vector_type(8)));
typedef __bf16 bf16x8 __attribute__((ext_vector_type(8)));
typedef float f32x4 __attribute__((ext_vector_type(4)));
typedef unsigned short ushort4v __attribute__((ext_vector_type(4)));
typedef unsigned int uint4v __attribute__((ext_vector_type(4)));

static __device__ __forceinline__ bf16x8 as_bf(s16x8 v) {
    return __builtin_bit_cast(bf16x8, v);
}

#define BATCH 64
#define CH    64
#define HH    56
#define WW    56
#define HW    3136
#define M_TOT 200704
#define TPAD  60

static __device__ __forceinline__ ushort sign_bf16(float v) {
    return v > 0.f ? (ushort)0x3F80u : (v < 0.f ? (ushort)0xBF80u : (ushort)0u);
}

// Branchless zero-mask: keep value iff valid (compiles to v_cndmask, no branch)
static __device__ __forceinline__ s16x8 mask_s16x8(s16x8 v, bool valid) {
    uint4v u = __builtin_bit_cast(uint4v, v);
    u.x = valid ? u.x : 0u;
    u.y = valid ? u.y : 0u;
    u.z = valid ? u.z : 0u;
    u.w = valid ? u.w : 0u;
    return __builtin_bit_cast(s16x8, u);
}

// Kernel 1 (grid = 3584 transpose blocks + 64 weight blocks):
//  blk < 3584:  S[b][h][w][c] = bf16(sign(x[b][c][h][w] + bias0[c]))
//  blk >= 3584: p = blk-3584 -> fold weight signs + BN constants for channel p
__global__ __launch_bounds__(256)
void sign_prep_kernel(const float* __restrict__ x,
                      const float* __restrict__ bias0,
                      const float* __restrict__ w,
                      const float* __restrict__ gamma,
                      const float* __restrict__ beta,
                      const float* __restrict__ rmean,
                      const float* __restrict__ rvar,
                      const float* __restrict__ bias1,
                      const float* __restrict__ alpha,
                      const float* __restrict__ bias2,
                      ushort* __restrict__ S,
                      ushort* __restrict__ wsgn,
                      float* __restrict__ consts) {
    __shared__ ushort tile[64 * TPAD];
    __shared__ float red[4];
    const int tid = threadIdx.x;
    const int blk = blockIdx.x;

    if (blk < BATCH * HH) {
        const int b = blk / HH;
        const int h = blk - b * HH;
        const float* xp = x + (size_t)b * CH * HW + (size_t)h * WW;

        for (int i = tid; i < CH * 14; i += 256) {
            int c = i / 14, q = i - c * 14;
            float4 v = *(const float4*)(xp + (size_t)c * HW + q * 4);
            float bz = bias0[c];
            ushort4v u;
            u.x = sign_bf16(v.x + bz);
            u.y = sign_bf16(v.y + bz);
            u.z = sign_bf16(v.z + bz);
            u.w = sign_bf16(v.w + bz);
            *(ushort4v*)(tile + c * TPAD + q * 4) = u;
        }
        __syncthreads();

        ushort* Sp = S + (size_t)blk * (WW * CH);
        for (int j = tid; j < WW * 8; j += 256) {
            int cb = j & 7, ww = j >> 3;
            s16x8 r;
#pragma unroll
            for (int k = 0; k < 8; ++k)
                r[k] = (short)tile[(cb * 8 + k) * TPAD + ww];
            *(s16x8*)(Sp + ww * 64 + cb * 8) = r;
        }
    } else {
        const int p = blk - BATCH * HH;
        const float* wp = w + p * 576;
        float s = 0.f;
        for (int i = tid; i < 576; i += 256) s += fabsf(wp[i]);
#pragma unroll
        for (int off = 32; off > 0; off >>= 1) s += __shfl_down(s, off);
        const int lane = tid & 63, wv = tid >> 6;
        if (lane == 0) red[wv] = s;
        __syncthreads();
        if (tid == 0) {
            float scale = (red[0] + red[1] + red[2] + red[3]) * (1.0f / 576.0f);
            float inv = gamma[p] * rsqrtf(rvar[p] + 1e-5f);
            consts[p]       = scale * inv;
            consts[64 + p]  = beta[p] - rmean[p] * inv + bias1[p];
            consts[128 + p] = alpha[p];
            consts[192 + p] = bias2[p];
        }
        for (int i = tid; i < 576; i += 256) {
            int c = i / 9, tap = i - c * 9;
            wsgn[((tap << 6) + p) * 64 + c] = sign_bf16(wp[i]);
        }
    }
}

// Kernel 2: implicit-GEMM binary conv, no LDS, branchless clamped loads,
// explicit next-tap A prefetch. 256 thr (4 waves) x 32 pos/wave = 128 pos/block.
// Grid 1568 (= 8*196, XCD-swizzled).
__global__ __launch_bounds__(256, 5)
void conv_kernel(const ushort* __restrict__ S,
                 const ushort* __restrict__ wsgn,
                 const float* __restrict__ x,
                 const float* __restrict__ consts,
                 float* __restrict__ out) {
    const int lane = threadIdx.x & 63;
    const int wv = threadIdx.x >> 6;

    // bijective XCD swizzle: 1568 = 8 * 196
    const int bid = blockIdx.x;
    const int wg = (bid & 7) * 196 + (bid >> 3);
    const int mbase = (wg << 7) + (wv << 5);

    const int lr = lane & 15;   // A-row (position) / D-col (channel)
    const int cg = lane >> 4;   // k-group 0..3

    int bb[2], hb[2], wb[2];
#pragma unroll
    for (int mt = 0; mt < 2; ++mt) {
        int m = mbase + (mt << 4) + lr;
        bb[mt] = m / HW;
        int r = m - bb[mt] * HW;
        hb[mt] = r / WW;
        wb[mt] = r - hb[mt] * WW;
    }

    f32x4 acc[2][4] = {};

    // --- A-load helper (branchless): clamped address + cndmask zeroing ---
    auto load_a = [&](int mt, int dh, int dw, s16x8& a0, s16x8& a1) {
        int hh = hb[mt] + dh, ww = wb[mt] + dw;
        bool valid = ((unsigned)hh < (unsigned)HH) & ((unsigned)ww < (unsigned)WW);
        int hc = min(max(hh, 0), HH - 1);
        int wc = min(max(ww, 0), WW - 1);
        const ushort* sp = S + ((((size_t)bb[mt] * HH + hc) * WW + wc) << 6) + (cg << 3);
        s16x8 r0 = *(const s16x8*)(sp);
        s16x8 r1 = *(const s16x8*)(sp + 32);
        a0 = mask_s16x8(r0, valid);
        a1 = mask_s16x8(r1, valid);
    };

    s16x8 a[2][2];
    load_a(0, -1, -1, a[0][0], a[0][1]);
    load_a(1, -1, -1, a[1][0], a[1][1]);

#pragma unroll
    for (int tap = 0; tap < 9; ++tap) {
        s16x8 an[2][2];
        if (tap < 8) {
            const int dh = (tap + 1) / 3 - 1, dw = (tap + 1) % 3 - 1;
            load_a(0, dh, dw, an[0][0], an[0][1]);
            load_a(1, dh, dw, an[1][0], an[1][1]);
        }
#pragma unroll
        for (int nt = 0; nt < 4; ++nt) {
            const ushort* bp = wsgn + (((tap << 6) + (nt << 4) + lr) << 6) + (cg << 3);
            s16x8 b0 = *(const s16x8*)(bp);
            s16x8 b1 = *(const s16x8*)(bp + 32);
#pragma unroll
            for (int mt = 0; mt < 2; ++mt) {
                acc[mt][nt] = __builtin_amdgcn_mfma_f32_16x16x32_bf16(
                    as_bf(a[mt][0]), as_bf(b0), acc[mt][nt], 0, 0, 0);
                acc[mt][nt] = __builtin_amdgcn_mfma_f32_16x16x32_bf16(
                    as_bf(a[mt][1]), as_bf(b1), acc[mt][nt], 0, 0, 0);
            }
        }
        if (tap < 8) {
#pragma unroll
            for (int mt = 0; mt < 2; ++mt) {
                a[mt][0] = an[mt][0];
                a[mt][1] = an[mt][1];
            }
        }
    }

    // Epilogue: out = PReLU(acc*A_mul + B_add + residual) + bias2
#pragma unroll
    for (int mt = 0; mt < 2; ++mt) {
        int m0 = mbase + (mt << 4) + (cg << 2);
        int b = m0 / HW;
        int r = m0 - b * HW;
        int h = r / WW;
        int w0 = r - h * WW;
#pragma unroll
        for (int nt = 0; nt < 4; ++nt) {
            int p = (nt << 4) + lr;
            float am = consts[p];
            float bd = consts[64 + p];
            float al = consts[128 + p];
            float b2 = consts[192 + p];
            size_t off = ((((size_t)b << 6) + p) * HH + h) * WW + w0;
            float4 res = *(const float4*)(x + off);
            float4 o;
            const float* accp = (const float*)&acc[mt][nt];
            const float* rp = (const float*)&res;
            float* op = (float*)&o;
#pragma unroll
            for (int rr = 0; rr < 4; ++rr) {
                float v = accp[rr] * am + bd + rp[rr];
                v = v >= 0.f ? v : al * v;
                op[rr] = v + b2;
            }
            *(float4*)(out + off) = o;
        }
    }
}

extern "C" void kernel_launch(void* const* d_in, const int* in_sizes, int n_in,
                              void* d_out, int out_size, void* d_ws, size_t ws_size,
                              hipStream_t stream) {
    const float* x     = (const float*)d_in[0];
    const float* bias0 = (const float*)d_in[1];
    const float* w     = (const float*)d_in[2];
    const float* gamma = (const float*)d_in[3];
    const float* beta  = (const float*)d_in[4];
    const float* rmean = (const float*)d_in[5];
    const float* rvar  = (const float*)d_in[6];
    const float* bias1 = (const float*)d_in[7];
    const float* alpha = (const float*)d_in[8];
    const float* bias2 = (const float*)d_in[9];
    float* out = (float*)d_out;

    char* ws = (char*)d_ws;
    float* consts = (float*)ws;                       // 256 f32 = 1 KB
    ushort* wsgn  = (ushort*)(ws + 1024);             // 73,728 B
    ushort* S     = (ushort*)(ws + 1024 + 73728);     // 25,690,112 B

    sign_prep_kernel<<<BATCH * HH + 64, 256, 0, stream>>>(
        x, bias0, w, gamma, beta, rmean, rvar, bias1, alpha, bias2, S, wsgn, consts);

    conv_kernel<<<M_TOT / 128, 256, 0, stream>>>(S, wsgn, x, consts, out);
}

// Round 4
// 69.904 us; speedup vs baseline: 1.7195x; 1.7195x over previous
//
#include <hip/hip_runtime.h>

#define BATCH 64
#define CH    64
#define HH    56
#define WW    56
#define HW    3136
#define NROWS (BATCH * HH)   // 3584 sign rows
#define PBLK  896            // pack blocks (4 rows each)

// Kernel 1: pack signs via ballot (lane = channel), NCHW -> [b][h][w] uint64.
//  blk < PBLK: 4 rows (b,h) per block, one per wave.
//  blk >= PBLK: weight fold for p = blk-PBLK: abs-mean + BN consts + packed sign bits.
__global__ __launch_bounds__(256)
void pack_kernel(const float* __restrict__ x,
                 const float* __restrict__ bias0,
                 const float* __restrict__ w,
                 const float* __restrict__ gamma,
                 const float* __restrict__ beta,
                 const float* __restrict__ rmean,
                 const float* __restrict__ rvar,
                 const float* __restrict__ bias1,
                 const float* __restrict__ alpha,
                 const float* __restrict__ bias2,
                 unsigned long long* __restrict__ Spk,
                 unsigned long long* __restrict__ wbits,
                 float* __restrict__ consts) {
    const int tid = threadIdx.x;
    const int lane = tid & 63;
    const int wv = tid >> 6;
    const int blk = blockIdx.x;

    if (blk < PBLK) {
        const int row = blk * 4 + wv;          // = b*56 + h
        const float* xp = x + ((size_t)((row / HH) * CH + lane)) * HW + (row % HH) * WW;
        const float bz = bias0[lane];
        unsigned long long* sp = Spk + (size_t)row * WW;
#pragma unroll
        for (int q = 0; q < 14; ++q) {
            float4 v = *(const float4*)(xp + q * 4);
            unsigned long long m0 = __ballot(v.x + bz > 0.f);
            unsigned long long m1 = __ballot(v.y + bz > 0.f);
            unsigned long long m2 = __ballot(v.z + bz > 0.f);
            unsigned long long m3 = __ballot(v.w + bz > 0.f);
            if (lane == 0) {
                sp[q * 4 + 0] = m0;
                sp[q * 4 + 1] = m1;
                sp[q * 4 + 2] = m2;
                sp[q * 4 + 3] = m3;
            }
        }
    } else {
        __shared__ float red[4];
        const int p = blk - PBLK;
        const float* wp = w + p * 576;
        float s = 0.f;
        for (int i = tid; i < 576; i += 256) s += fabsf(wp[i]);
#pragma unroll
        for (int off = 32; off > 0; off >>= 1) s += __shfl_down(s, off);
        if (lane == 0) red[wv] = s;
        __syncthreads();
        if (tid == 0) {
            float scale = (red[0] + red[1] + red[2] + red[3]) * (1.0f / 576.0f);
            float inv = gamma[p] * rsqrtf(rvar[p] + 1e-5f);
            consts[p]       = scale * inv;                         // A_mul
            consts[64 + p]  = beta[p] - rmean[p] * inv + bias1[p]; // B_add
            consts[128 + p] = alpha[p];
            consts[192 + p] = bias2[p];
        }
        if (wv == 0) {
            // pack weight signs: bit c of wbits[tap*64+p] = (w[p][c][tap] > 0)
#pragma unroll
            for (int t = 0; t < 9; ++t) {
                float v = wp[lane * 9 + t];
                unsigned long long m = __ballot(v > 0.f);
                if (lane == 0) wbits[t * 64 + p] = m;
            }
        }
    }
}

// Kernel 2: XNOR-popcount conv + fused BN/residual/PReLU/bias epilogue.
// Block = 256 thr (4 waves); wave = one (b,h) row, lane = w (56 active).
// dot_p = 64*nvalid - 2 * sum_t popcnt((a_t ^ w_t) & mask_t)
__global__ __launch_bounds__(256)
void conv_pop_kernel(const unsigned long long* __restrict__ Spk,
                     const unsigned long long* __restrict__ wbits,
                     const float* __restrict__ x,
                     const float* __restrict__ consts,
                     float* __restrict__ out) {
    __shared__ unsigned long long wsm[576];
    __shared__ float csm[256];

    const int tid = threadIdx.x;
    csm[tid] = consts[tid];
    for (int i = tid; i < 1152; i += 256)
        ((unsigned int*)wsm)[i] = ((const unsigned int*)wbits)[i];
    __syncthreads();

    // bijective XCD swizzle: 896 = 8 * 112
    const int bid = blockIdx.x;
    const int wg = (bid & 7) * 112 + (bid >> 3);
    const int lane = tid & 63;
    const int wv = tid >> 6;
    const int b = wg / 14;
    const int h = (wg % 14) * 4 + wv;
    const int wcol = lane;
    const bool active = wcol < WW;

    const unsigned long long* Sb = Spk + (size_t)b * HW;

    unsigned long long a[9];
    unsigned int mk[9];
    int nvalid = 0;
#pragma unroll
    for (int t = 0; t < 9; ++t) {
        int dh = t / 3 - 1, dw = t % 3 - 1;
        int hh = h + dh, ww = wcol + dw;
        bool valid = ((unsigned)hh < (unsigned)HH) & ((unsigned)ww < (unsigned)WW);
        int hc = min(max(hh, 0), HH - 1);
        int wc = min(max(ww, 0), WW - 1);
        a[t] = Sb[hc * WW + wc];
        mk[t] = valid ? 0xFFFFFFFFu : 0u;
        nvalid += valid ? 1 : 0;
    }
    const float dbase = (float)(nvalid << 6);

    // clamped residual base (inactive lanes read lane-0's data, never OOB)
    const size_t xoff = ((size_t)b * CH) * HW + h * WW + (active ? wcol : 0);

#pragma unroll 4
    for (int p = 0; p < 64; ++p) {
        unsigned int P = 0;
#pragma unroll
        for (int t = 0; t < 9; ++t) {
            unsigned long long v = a[t] ^ wsm[t * 64 + p];
            P += __popc((unsigned int)v & mk[t]);
            P += __popc((unsigned int)(v >> 32) & mk[t]);
        }
        const float am = csm[p];
        const float bd = csm[64 + p];
        const float al = csm[128 + p];
        const float b2 = csm[192 + p];
        const float res = x[xoff + (size_t)p * HW];
        float v = fmaf(-2.f * am, (float)P, fmaf(am, dbase, bd)) + res;
        v = v >= 0.f ? v : al * v;
        if (active) out[xoff + (size_t)p * HW] = v + b2;
    }
}

extern "C" void kernel_launch(void* const* d_in, const int* in_sizes, int n_in,
                              void* d_out, int out_size, void* d_ws, size_t ws_size,
                              hipStream_t stream) {
    const float* x     = (const float*)d_in[0];
    const float* bias0 = (const float*)d_in[1];
    const float* w     = (const float*)d_in[2];
    const float* gamma = (const float*)d_in[3];
    const float* beta  = (const float*)d_in[4];
    const float* rmean = (const float*)d_in[5];
    const float* rvar  = (const float*)d_in[6];
    const float* bias1 = (const float*)d_in[7];
    const float* alpha = (const float*)d_in[8];
    const float* bias2 = (const float*)d_in[9];
    float* out = (float*)d_out;

    char* ws = (char*)d_ws;
    float* consts            = (float*)ws;                    // 1 KB
    unsigned long long* wbits = (unsigned long long*)(ws + 1024);   // 4.6 KB
    unsigned long long* Spk   = (unsigned long long*)(ws + 8192);   // 1.6 MB

    pack_kernel<<<PBLK + 64, 256, 0, stream>>>(
        x, bias0, w, gamma, beta, rmean, rvar, bias1, alpha, bias2, Spk, wbits, consts);

    conv_pop_kernel<<<PBLK, 256, 0, stream>>>(Spk, wbits, x, consts, out);
}

// Round 5
// 44.031 us; speedup vs baseline: 2.7300x; 1.5876x over previous
//
#include <hip/hip_runtime.h>

typedef unsigned long long u64;

#define BATCH 64
#define CH    64
#define HH    56
#define WW    56
#define HW    3136
#define NROWS (BATCH * HH)   // 3584
#define PBLK  896            // pack blocks (4 rows each)

// Kernel 1: pack sign bits + fold all weight/BN constants.
//  blk < PBLK : 4 rows (b,h), one per wave; lane = channel; ballot-pack; coalesced store.
//  blk >= PBLK: p = blk-PBLK. abs-mean, BN fold, packed weight bits, K table, c4 table.
__global__ __launch_bounds__(256)
void pack_kernel(const float* __restrict__ x,
                 const float* __restrict__ bias0,
                 const float* __restrict__ w,
                 const float* __restrict__ gamma,
                 const float* __restrict__ beta,
                 const float* __restrict__ rmean,
                 const float* __restrict__ rvar,
                 const float* __restrict__ bias1,
                 const float* __restrict__ alpha,
                 const float* __restrict__ bias2,
                 u64* __restrict__ Spk,
                 u64* __restrict__ wbits,
                 float* __restrict__ kc,      // [wc][lc][64]  (576 f32)
                 float4* __restrict__ c4) {   // [64] {-2am, al, b2, 0}
    const int tid = threadIdx.x;
    const int lane = tid & 63;
    const int wv = tid >> 6;
    const int blk = blockIdx.x;

    if (blk < PBLK) {
        const int row = blk * 4 + wv;          // = b*56 + h
        const float* xp = x + ((size_t)((row / HH) * CH + lane)) * HW + (row % HH) * WW;
        const float bz = bias0[lane];
        u64 mine = 0;
#pragma unroll
        for (int q = 0; q < 14; ++q) {
            float4 v = *(const float4*)(xp + q * 4);
            u64 m0 = __ballot(v.x + bz > 0.f);
            u64 m1 = __ballot(v.y + bz > 0.f);
            u64 m2 = __ballot(v.z + bz > 0.f);
            u64 m3 = __ballot(v.w + bz > 0.f);
            mine = (lane == q * 4 + 0) ? m0 : mine;
            mine = (lane == q * 4 + 1) ? m1 : mine;
            mine = (lane == q * 4 + 2) ? m2 : mine;
            mine = (lane == q * 4 + 3) ? m3 : mine;
        }
        if (lane < WW) Spk[(size_t)row * WW + lane] = mine;
    } else {
        __shared__ float red[4];
        const int p = blk - PBLK;
        const float* wp = w + p * 576;
        float s = 0.f;
        for (int i = tid; i < 576; i += 256) s += fabsf(wp[i]);
#pragma unroll
        for (int off = 32; off > 0; off >>= 1) s += __shfl_down(s, off);
        if (lane == 0) red[wv] = s;
        __syncthreads();

        u64 m[9];
        if (wv == 0) {
#pragma unroll
            for (int t = 0; t < 9; ++t) {
                m[t] = __ballot(wp[lane * 9 + t] > 0.f);   // bit c = sign(w[p][c][t])
                if (lane == 0) wbits[t * 64 + p] = m[t];
            }
        }
        if (tid == 0) {
            float scale = (red[0] + red[1] + red[2] + red[3]) * (1.0f / 576.0f);
            float inv = gamma[p] * rsqrtf(rvar[p] + 1e-5f);
            float am = scale * inv;
            float bd = beta[p] - rmean[p] * inv + bias1[p];
            float pt[9];
#pragma unroll
            for (int t = 0; t < 9; ++t) pt[t] = (float)__popcll(m[t]);
            // Cinv per (wave h-class wc, lane w-class lc); nv = #valid taps
            const float cL = pt[0] + pt[3] + pt[6];   // dw=-1 column
            const float cR = pt[2] + pt[5] + pt[8];   // dw=+1 column
            const float rT = pt[0] + pt[1] + pt[2];   // dh=-1 row
            const float rB = pt[6] + pt[7] + pt[8];   // dh=+1 row
            float Ci[3][3] = {
                {0.f,      cL,                      cR},
                {rT,       rT + pt[3] + pt[6],      rT + pt[5] + pt[8]},
                {rB,       rB + pt[0] + pt[3],      rB + pt[2] + pt[5]}};
            float nv[3][3] = {{9, 6, 6}, {6, 4, 4}, {6, 4, 4}};
#pragma unroll
            for (int wc = 0; wc < 3; ++wc)
#pragma unroll
                for (int lc = 0; lc < 3; ++lc)
                    kc[wc * 192 + lc * 64 + p] =
                        fmaf(am, 64.f * nv[wc][lc] + 2.f * Ci[wc][lc], bd);
            c4[p] = make_float4(-2.f * am, alpha[p], bias2[p], 0.f);
        }
    }
}

// Kernel 2: XNOR-popcount conv, premasked A, K-folded boundary correction.
// 256 thr = 4 waves = 2 rows x 2 p-halves; wave: 1 row x 32 channels.
// Grid 1792 (=8*224, XCD-swizzled).
__global__ __launch_bounds__(256, 6)
void conv_pop_kernel(const u64* __restrict__ Spk,
                     const u64* __restrict__ wbits,
                     const float* __restrict__ kc,
                     const float4* __restrict__ c4,
                     const float* __restrict__ x,
                     float* __restrict__ out) {
    __shared__ __align__(16) u64 wsm2[64 * 10];   // [p][t] (pad 10 for 16B align)
    __shared__ float kcsm[576];
    __shared__ float4 c4sm[64];

    const int tid = threadIdx.x;
    for (int i = tid; i < 576; i += 256) {
        int p = i / 9, t = i - p * 9;
        wsm2[p * 10 + t] = wbits[t * 64 + p];
        kcsm[i] = kc[i];
    }
    if (tid < 64) c4sm[tid] = c4[tid];
    __syncthreads();

    // bijective XCD swizzle: 1792 = 8 * 224
    const int bid = blockIdx.x;
    const int wg = (bid & 7) * 224 + (bid >> 3);
    const int lane = tid & 63;
    const int wv = tid >> 6;
    const int row = wg * 2 + (wv & 1);
    const int ph = (wv >> 1) * 32;
    const int b = row / HH;
    const int h = row - b * HH;
    const int wcol = min(lane, WW - 1);
    const bool active = lane < WW;

    // load + premask the 9 taps' activation words
    const u64* Sb = Spk + (size_t)b * HW;
    u64 a[9];
#pragma unroll
    for (int t = 0; t < 9; ++t) {
        int dh = t / 3 - 1, dw = t % 3 - 1;
        int hh = h + dh, ww = wcol + dw;
        bool valid = ((unsigned)hh < (unsigned)HH) & ((unsigned)ww < (unsigned)WW);
        int hc = min(max(hh, 0), HH - 1);
        int wc2 = min(max(ww, 0), WW - 1);
        a[t] = Sb[hc * WW + wc2] & (valid ? ~0ull : 0ull);
    }

    const int wclass = (h == 0) ? 1 : (h == HH - 1) ? 2 : 0;
    const float* kp = kcsm + wclass * 192 +
                      ((lane == 0) ? 64 : (lane == WW - 1) ? 128 : 0);

    const size_t xbase = (size_t)b * CH * HW + (size_t)h * WW + wcol;

#pragma unroll 4
    for (int i = 0; i < 32; ++i) {
        const int p = ph + i;
        const u64* wp = wsm2 + p * 10;
        unsigned int P = 0;
#pragma unroll
        for (int t = 0; t < 9; ++t) {
            u64 v = a[t] ^ wp[t];
            P += __popc((unsigned int)v);
            P += __popc((unsigned int)(v >> 32));
        }
        const float4 cc = c4sm[p];
        const float k = kp[p];
        const size_t off = xbase + (size_t)p * HW;
        const float res = x[off];
        float v = fmaf(cc.x, (float)P, k) + res;
        v = v >= 0.f ? v : cc.y * v;
        v += cc.z;
        if (active) out[off] = v;
    }
}

extern "C" void kernel_launch(void* const* d_in, const int* in_sizes, int n_in,
                              void* d_out, int out_size, void* d_ws, size_t ws_size,
                              hipStream_t stream) {
    const float* x     = (const float*)d_in[0];
    const float* bias0 = (const float*)d_in[1];
    const float* w     = (const float*)d_in[2];
    const float* gamma = (const float*)d_in[3];
    const float* beta  = (const float*)d_in[4];
    const float* rmean = (const float*)d_in[5];
    const float* rvar  = (const float*)d_in[6];
    const float* bias1 = (const float*)d_in[7];
    const float* alpha = (const float*)d_in[8];
    const float* bias2 = (const float*)d_in[9];
    float* out = (float*)d_out;

    char* ws = (char*)d_ws;
    u64* wbits = (u64*)ws;                       // 4,608 B
    float* kc  = (float*)(ws + 4608);            // 2,304 B
    float4* c4 = (float4*)(ws + 8192);           // 1,024 B
    u64* Spk   = (u64*)(ws + 16384);             // 1,605,632 B

    pack_kernel<<<PBLK + 64, 256, 0, stream>>>(
        x, bias0, w, gamma, beta, rmean, rvar, bias1, alpha, bias2,
        Spk, wbits, kc, c4);

    conv_pop_kernel<<<NROWS / 2, 256, 0, stream>>>(Spk, wbits, kc, c4, x, out);
}